// Round 2
// baseline (555.710 us; speedup 1.0000x reference)
//
#include <hip/hip_runtime.h>
#include <math.h>

#define NEGINF (-INFINITY)

typedef unsigned int u32;
typedef unsigned long long u64;

// One DPP max stage: x = max(x, lanes-moved(x)). bound_ctrl=false + old=x makes
// invalid source lanes contribute x itself (identity for max).
template <int CTRL>
__device__ __forceinline__ float dppmax(float x) {
    int xi = __float_as_int(x);
    int yi = __builtin_amdgcn_update_dpp(xi, xi, CTRL, 0xf, 0xf, false);
    return fmaxf(x, __int_as_float(yi));
}

// Wave64 max via DPP (VALU latency, no LDS): row_shr 1/2/4/8 then row_bcast 15/31.
__device__ __forceinline__ float wave_max64(float x) {
    x = dppmax<0x111>(x);   // row_shr:1
    x = dppmax<0x112>(x);   // row_shr:2
    x = dppmax<0x114>(x);   // row_shr:4
    x = dppmax<0x118>(x);   // row_shr:8
    x = dppmax<0x142>(x);   // row_bcast:15
    x = dppmax<0x143>(x);   // row_bcast:31
    return __int_as_float(__builtin_amdgcn_readlane(__float_as_int(x), 63));
}

// Wave argmax over (v, idx), tie-break lowest idx (matches jnp.argmax
// first-occurrence). Fast path: single lane holds the max -> one readlane.
__device__ __forceinline__ void wave_argmax(float v, int idx, float& out_v, int& out_idx) {
    float mv = wave_max64(v);
    unsigned long long mask = __ballot(v == mv);
    int ln = (int)__builtin_ctzll(mask);
    int bi = __builtin_amdgcn_readlane(idx, ln);
    unsigned long long rest = mask & (mask - 1);
    if (rest) {                       // wave-uniform, almost never taken
        while (rest) {
            int l2 = (int)__builtin_ctzll(rest); rest &= rest - 1;
            int b2 = __builtin_amdgcn_readlane(idx, l2);
            if (b2 < bi) bi = b2;
        }
    }
    out_v = mv; out_idx = bi;
}

// Consume a pending row rescan: w = this lane's 4 columns (4*lane..4*lane+3)
// of row `row`, masked by the lane's colmask bits; exact (max, argcol) via
// wave argmax; owner lane refreshes the row cache (row becomes FRESH).
__device__ __forceinline__ void consume_row(int row, float4 w, u32 colmask, int lane,
                                            float (&rv)[4], int (&rc)[4]) {
    float m0 = (colmask & 1u) ? NEGINF : w.x;
    float m1 = (colmask & 2u) ? NEGINF : w.y;
    float m2 = (colmask & 4u) ? NEGINF : w.z;
    float m3 = (colmask & 8u) ? NEGINF : w.w;
    float lv = m0; int lf = 4 * lane;
    if (m1 > lv) { lv = m1; lf = 4 * lane + 1; }
    if (m2 > lv) { lv = m2; lf = 4 * lane + 2; }
    if (m3 > lv) { lv = m3; lf = 4 * lane + 3; }
    float nv; int nc;
    wave_argmax(lv, lf, nv, nc);
    if (lane == (row & 63)) {
        const int rj = row >> 6;
#pragma unroll
        for (int j = 0; j < 4; ++j) if (j == rj) { rv[j] = nv; rc[j] = nc; }
    }
}

// One wave (64 lanes) per batch. Lane l owns rows {j*64+l : j=0..3} and the
// column-mask bits for cols 4l..4l+3.
// Row cache states (rc[j]): 0..255 = FRESH (rv exact max, rc its argcol);
//   256 = STALE (rv is an UPPER BOUND on the true max; a refill load for the
//         row is pending in one of 4 static register slots);
//   257 = DEAD (assigned; rv = NEGINF).
// A stale row participates in the argmax with its bound and synthetic col 0
// (lowest flat -> ties resolve toward it, forcing resolution). If the argmax
// winner is fresh, it is exact (every stale TRUE max <= its bound < winner).
// If a stale bound wins, we block on just that row's pending load, refresh,
// and re-reduce (rare). Pending loads are otherwise consumed lazily when
// >= 2 steps old, keeping L3 latency OFF the sequential critical chain.
__global__ __launch_bounds__(64, 1) void greedy_perm_kernel(
        const float* __restrict__ soft, float* __restrict__ out) {
    const int b = blockIdx.x;
    const int lane = threadIdx.x;
    const size_t base = (size_t)b << 16;          // b * 256 * 256
    const float* sc = soft + base;
    float* ob = out + base;

    float rv[4];
    int   rc[4];
#pragma unroll
    for (int j = 0; j < 4; ++j) { rv[j] = NEGINF; rc[j] = 0; }

    const float4 zero4 = make_float4(0.f, 0.f, 0.f, 0.f);

    // ---- initial per-row scans, 16 loads in flight, fused zero-fill of out ----
    for (int k = 0; k < 64; k += 4) {
        float4 w[4][4];
#pragma unroll
        for (int j = 0; j < 4; ++j) {
            const float4* rp = (const float4*)(sc + (size_t)(j * 64 + lane) * 256);
#pragma unroll
            for (int kk = 0; kk < 4; ++kk) w[j][kk] = rp[k + kk];
        }
#pragma unroll
        for (int j = 0; j < 4; ++j) {
            float4* op = (float4*)(ob + (size_t)(j * 64 + lane) * 256);
#pragma unroll
            for (int kk = 0; kk < 4; ++kk) op[k + kk] = zero4;
        }
#pragma unroll
        for (int j = 0; j < 4; ++j) {
#pragma unroll
            for (int kk = 0; kk < 4; ++kk) {
                const float4 ww = w[j][kk];
                const int bc = 4 * (k + kk);
                if (ww.x > rv[j]) { rv[j] = ww.x; rc[j] = bc + 0; }
                if (ww.y > rv[j]) { rv[j] = ww.y; rc[j] = bc + 1; }
                if (ww.z > rv[j]) { rv[j] = ww.z; rc[j] = bc + 2; }
                if (ww.w > rv[j]) { rv[j] = ww.w; rc[j] = bc + 3; }
            }
        }
    }

    // Drain zero-stores before any 1.0 store can target the same address.
    __threadfence_block();

    u32 colmask = 0;   // 4 bits: cols 4*lane..4*lane+3 assigned?

    // 4 static pending-refill slots (wave-uniform metadata, per-lane float4 data).
    float4 d0 = zero4, d1 = zero4, d2 = zero4, d3 = zero4;
    int sr0 = -1, sr1 = -1, sr2 = -1, sr3 = -1;   // row id, -1 = free
    int age0 = 0, age1 = 0, age2 = 0, age3 = 0;

    // ---- 256 sequential greedy steps ----
    for (int step = 0; step < 256; ++step) {
        float gv; int gf, r, cc;
        // argmax + stale-winner resolve loop (<= 5 iterations, usually 1)
        for (;;) {
            float bv = rv[0]; int bf = (lane << 8) | (rc[0] & 255);
#pragma unroll
            for (int j = 1; j < 4; ++j) {
                const float vj = rv[j];
                const int   fj = (((j << 6) + lane) << 8) | (rc[j] & 255);
                if (vj > bv || (vj == bv && fj < bf)) { bv = vj; bf = fj; }
            }
            wave_argmax(bv, bf, gv, gf);
            r  = gf >> 8;
            cc = gf & 255;
            // winner state: read the owner lane's rc for row r
            const int rj = r >> 6;
            int myc = rc[0];
#pragma unroll
            for (int j = 1; j < 4; ++j) if (j == rj) myc = rc[j];
            const int wc = __builtin_amdgcn_readlane(myc, r & 63);
            if (wc < 256) break;                  // fresh winner: exact, cc == wc
            // stale winner: block on its pending slot, refresh, re-reduce
            if      (sr0 == r) { consume_row(r, d0, colmask, lane, rv, rc); sr0 = -1; }
            else if (sr1 == r) { consume_row(r, d1, colmask, lane, rv, rc); sr1 = -1; }
            else if (sr2 == r) { consume_row(r, d2, colmask, lane, rv, rc); sr2 = -1; }
            else               { consume_row(r, d3, colmask, lane, rv, rc); sr3 = -1; }
        }

        if (lane == 0) ob[gf] = 1.0f;            // hard[r][cc] = 1
        if (lane == (r & 63)) {                  // row r assigned -> dead
            const int rj = r >> 6;
#pragma unroll
            for (int j = 0; j < 4; ++j) if (j == rj) { rv[j] = NEGINF; rc[j] = 257; }
        }
        if (lane == (cc >> 2)) colmask |= 1u << (cc & 3);

        // rows whose cached argmax column was just taken: mark STALE (rv stays
        // as upper bound) and issue an async refill load into a free slot.
#pragma unroll
        for (int j = 0; j < 4; ++j) {
            u64 m = __ballot(rc[j] == cc);       // fresh rows only (sentinels != cc)
            while (m) {
                const int ln = (int)__builtin_ctzll(m); m &= m - 1;
                const int row = (j << 6) + ln;
                if (lane == ln) rc[j] = 256;     // stale
                const float4* rp = (const float4*)(sc + ((size_t)row << 8)) + lane;
                if      (sr0 < 0) { d0 = *rp; sr0 = row; age0 = 0; }
                else if (sr1 < 0) { d1 = *rp; sr1 = row; age1 = 0; }
                else if (sr2 < 0) { d2 = *rp; sr2 = row; age2 = 0; }
                else if (sr3 < 0) { d3 = *rp; sr3 = row; age3 = 0; }
                else {                            // all slots busy (rare): sync path
                    float4 w = *rp;
                    consume_row(row, w, colmask, lane, rv, rc);
                }
            }
        }

        // lazy consume: one pending slot aged >= 2 steps (load long landed),
        // plus a second when a backlog builds. Off the critical chain.
        ++age0; ++age1; ++age2; ++age3;
        if      (sr0 >= 0 && age0 >= 2) { consume_row(sr0, d0, colmask, lane, rv, rc); sr0 = -1; }
        else if (sr1 >= 0 && age1 >= 2) { consume_row(sr1, d1, colmask, lane, rv, rc); sr1 = -1; }
        else if (sr2 >= 0 && age2 >= 2) { consume_row(sr2, d2, colmask, lane, rv, rc); sr2 = -1; }
        else if (sr3 >= 0 && age3 >= 2) { consume_row(sr3, d3, colmask, lane, rv, rc); sr3 = -1; }
        const int occ = (sr0 >= 0) + (sr1 >= 0) + (sr2 >= 0) + (sr3 >= 0);
        if (occ >= 3) {
            if      (sr0 >= 0 && age0 >= 2) { consume_row(sr0, d0, colmask, lane, rv, rc); sr0 = -1; }
            else if (sr1 >= 0 && age1 >= 2) { consume_row(sr1, d1, colmask, lane, rv, rc); sr1 = -1; }
            else if (sr2 >= 0 && age2 >= 2) { consume_row(sr2, d2, colmask, lane, rv, rc); sr2 = -1; }
            else if (sr3 >= 0 && age3 >= 2) { consume_row(sr3, d3, colmask, lane, rv, rc); sr3 = -1; }
        }
    }
}

extern "C" void kernel_launch(void* const* d_in, const int* in_sizes, int n_in,
                              void* d_out, int out_size, void* d_ws, size_t ws_size,
                              hipStream_t stream) {
    const float* soft = (const float*)d_in[0];
    float* out = (float*)d_out;
    const int n_batches = in_sizes[0] >> 16;   // elements / (256*256)

    // Output zero-fill is fused into the kernel (each block covers its slice).
    greedy_perm_kernel<<<n_batches, 64, 0, stream>>>(soft, out);
}

// Round 3
// 342.649 us; speedup vs baseline: 1.6218x; 1.6218x over previous
//
#include <hip/hip_runtime.h>
#include <math.h>

#define NEGINF (-INFINITY)

typedef unsigned int u32;
typedef unsigned long long u64;

#define RST 128  // rows staged in LDS (128 KiB dynamic shared)

// One DPP max stage: x = max(x, lanes-moved(x)). bound_ctrl=false + old=x makes
// invalid source lanes contribute x itself (identity for max).
template <int CTRL>
__device__ __forceinline__ float dppmax(float x) {
    int xi = __float_as_int(x);
    int yi = __builtin_amdgcn_update_dpp(xi, xi, CTRL, 0xf, 0xf, false);
    return fmaxf(x, __int_as_float(yi));
}

// Wave64 max via DPP: row_shr 1/2/4/8 then row_bcast 15/31, broadcast from lane 63.
__device__ __forceinline__ float wave_max64(float x) {
    x = dppmax<0x111>(x);   // row_shr:1
    x = dppmax<0x112>(x);   // row_shr:2
    x = dppmax<0x114>(x);   // row_shr:4
    x = dppmax<0x118>(x);   // row_shr:8
    x = dppmax<0x142>(x);   // row_bcast:15
    x = dppmax<0x143>(x);   // row_bcast:31
    return __int_as_float(__builtin_amdgcn_readlane(__float_as_int(x), 63));
}

// Wave argmax over (v, idx), tie-break lowest idx (matches jnp.argmax
// first-occurrence). Fast path: single lane holds the max -> one readlane.
__device__ __forceinline__ void wave_argmax(float v, int idx, float& out_v, int& out_idx) {
    float mv = wave_max64(v);
    u64 mask = __ballot(v == mv);
    int ln = (int)__builtin_ctzll(mask);
    int bi = __builtin_amdgcn_readlane(idx, ln);
    u64 rest = mask & (mask - 1);
    if (rest) {                       // wave-uniform, almost never taken
        while (rest) {
            int l2 = (int)__builtin_ctzll(rest); rest &= rest - 1;
            int b2 = __builtin_amdgcn_readlane(idx, l2);
            if (b2 < bi) bi = b2;
        }
    }
    out_v = mv; out_idx = bi;
}

// One wave (64 lanes) per batch. Lane l owns rows {j*64+l : j=0..3}:
//   rv[j]/rc[j] : row's current best (max value, argmax col) over untaken cols.
//                 rc==300 => row DEAD (assigned), rv=NEGINF.
//   sv[j]/scc[j]: row's spare = exact runner-up over untaken cols at the time it
//                 was computed, maintained eagerly (scc invalidated the step its
//                 col is taken). scc==300 => no spare.
// Lane l also owns the taken-bits for cols 4l..4l+3 (colmask).
// When a row's best col is taken: if a live spare exists, advance in-registers
// (exact: no value lies strictly between max2 and max1; col-asc ties preserved
// by strict-> updates). Otherwise cooperative rescan (LDS for rows < RSTT,
// global beyond), which also refills the spare via a second wave reduction.
template <int RSTT>
__global__ __launch_bounds__(64, 1) void greedy_perm_kernel(
        const float* __restrict__ soft, float* __restrict__ out) {
    extern __shared__ float smem[];               // RSTT rows x 256 floats
    const int b = blockIdx.x;
    const int lane = threadIdx.x;
    const size_t base = (size_t)b << 16;          // b * 256 * 256
    const float* sc = soft + base;
    float* ob = out + base;

    float rv[4], sv[4];
    int   rc[4], scc[4];
#pragma unroll
    for (int j = 0; j < 4; ++j) { rv[j] = NEGINF; rc[j] = 0; sv[j] = NEGINF; scc[j] = 300; }

    const float4 zero4 = make_float4(0.f, 0.f, 0.f, 0.f);

    // ---- initial per-row top-2 scan, 16 loads in flight, fused zero-fill of
    // ---- out, fused LDS staging of rows 0..RSTT-1 (chunk-XOR swizzled) ----
    for (int k = 0; k < 64; k += 4) {
        float4 w[4][4];
#pragma unroll
        for (int j = 0; j < 4; ++j) {
            const float4* rp = (const float4*)(sc + (size_t)(j * 64 + lane) * 256);
#pragma unroll
            for (int kk = 0; kk < 4; ++kk) w[j][kk] = rp[k + kk];
        }
#pragma unroll
        for (int j = 0; j < 4; ++j) {
            float4* op = (float4*)(ob + (size_t)(j * 64 + lane) * 256);
#pragma unroll
            for (int kk = 0; kk < 4; ++kk) op[k + kk] = zero4;
        }
        if (RSTT > 0) {
            // rows j*64+lane (j=0,1): store chunk c at slot c^lane -> 64 lanes'
            // 16B writes spread across banks (2 lanes/bank, free).
#pragma unroll
            for (int j = 0; j < 2; ++j) {
                float* lp = &smem[(j * 64 + lane) << 8];
#pragma unroll
                for (int kk = 0; kk < 4; ++kk)
                    *(float4*)&lp[((k + kk) ^ lane) << 2] = w[j][kk];
            }
        }
#pragma unroll
        for (int j = 0; j < 4; ++j) {
#pragma unroll
            for (int kk = 0; kk < 4; ++kk) {
                const float4 ww = w[j][kk];
                const int bc = 4 * (k + kk);
                const float e[4] = {ww.x, ww.y, ww.z, ww.w};
#pragma unroll
                for (int q = 0; q < 4; ++q) {
                    const float x = e[q];
                    const int   cx = bc + q;
                    const bool g1 = x > rv[j];
                    const bool g2 = x > sv[j];
                    sv[j]  = g1 ? rv[j] : (g2 ? x  : sv[j]);
                    scc[j] = g1 ? rc[j] : (g2 ? cx : scc[j]);
                    rv[j]  = g1 ? x  : rv[j];
                    rc[j]  = g1 ? cx : rc[j];
                }
            }
        }
    }

    // Drain zero-stores before any 1.0 store can target the same address.
    __threadfence_block();

    u32 colmask = 0;   // 4 bits: cols 4*lane..4*lane+3 assigned?

    // ---- 256 sequential greedy steps ----
    for (int step = 0; step < 256; ++step) {
        // A: argmax over cached row bests (flat = row*256 + col, lowest wins ties)
        float bv = rv[0];
        int   bf = (lane << 8) | (rc[0] & 255);
#pragma unroll
        for (int j = 1; j < 4; ++j) {
            const float vj = rv[j];
            const int   fj = (((j << 6) + lane) << 8) | (rc[j] & 255);
            if (vj > bv || (vj == bv && fj < bf)) { bv = vj; bf = fj; }
        }
        float gv; int gf;
        wave_argmax(bv, bf, gv, gf);
        const int r  = gf >> 8;
        const int cc = gf & 255;

        if (lane == 0) ob[gf] = 1.0f;            // hard[r][cc] = 1
        if (lane == (r & 63)) {                  // winner row -> dead
            const int rj = r >> 6;
#pragma unroll
            for (int j = 0; j < 4; ++j) if (j == rj) { rv[j] = NEGINF; rc[j] = 300; }
        }
        if (lane == (cc >> 2)) colmask |= 1u << (cc & 3);

        // spare invalidation: a spare whose col was just taken dies (eager).
#pragma unroll
        for (int j = 0; j < 4; ++j) if (scc[j] == cc) scc[j] = 300;

        // dirty rows (best col just taken): in-register advance when a live
        // spare exists; cooperative rescan otherwise.
#pragma unroll
        for (int j = 0; j < 4; ++j) {
            const bool dirty = (rc[j] == cc);
            const bool need  = dirty && (scc[j] == 300);
            if (dirty && !need) {                // exact advance, no memory
                rv[j] = sv[j]; rc[j] = scc[j];
                sv[j] = NEGINF; scc[j] = 300;
            }
            u64 m = __ballot(need);
            while (m) {
                const int ln = (int)__builtin_ctzll(m); m &= m - 1;
                const int row = (j << 6) + ln;
                // coalesced: 64 lanes x float4 = the whole 256-float row
                float4 w = (RSTT > 0 && row < RSTT)
                    ? *(const float4*)&smem[(row << 8) | (((lane ^ ln) & 63) << 2)]
                    : *(const float4*)(sc + ((size_t)row << 8) + (lane << 2));
                float m0 = (colmask & 1u) ? NEGINF : w.x;
                float m1 = (colmask & 2u) ? NEGINF : w.y;
                float m2 = (colmask & 4u) ? NEGINF : w.z;
                float m3 = (colmask & 8u) ? NEGINF : w.w;
                float lv = m0; int lf = 4 * lane;
                if (m1 > lv) { lv = m1; lf = 4 * lane + 1; }
                if (m2 > lv) { lv = m2; lf = 4 * lane + 2; }
                if (m3 > lv) { lv = m3; lf = 4 * lane + 3; }
                float nv; int nc;
                wave_argmax(lv, lf, nv, nc);     // fresh best of the row
                // runner-up: winner lane drops the winning col, reduce again
                const bool wl = (lane == (nc >> 2));
                if (wl && (nc & 3) == 0) m0 = NEGINF;
                if (wl && (nc & 3) == 1) m1 = NEGINF;
                if (wl && (nc & 3) == 2) m2 = NEGINF;
                if (wl && (nc & 3) == 3) m3 = NEGINF;
                float lv2 = m0; int lf2 = 4 * lane;
                if (m1 > lv2) { lv2 = m1; lf2 = 4 * lane + 1; }
                if (m2 > lv2) { lv2 = m2; lf2 = 4 * lane + 2; }
                if (m3 > lv2) { lv2 = m3; lf2 = 4 * lane + 3; }
                float nv2; int nc2;
                wave_argmax(lv2, lf2, nv2, nc2); // fresh spare of the row
                if (lane == ln) {
#pragma unroll
                    for (int jj = 0; jj < 4; ++jj) if (jj == j) {
                        rv[jj] = nv; rc[jj] = nc;
                        // softmax values are > 0; nv2 <= 0 means no untaken col left
                        sv[jj]  = nv2;
                        scc[jj] = (nv2 > 0.f) ? nc2 : 300;
                    }
                }
            }
        }
    }
}

extern "C" void kernel_launch(void* const* d_in, const int* in_sizes, int n_in,
                              void* d_out, int out_size, void* d_ws, size_t ws_size,
                              hipStream_t stream) {
    const float* soft = (const float*)d_in[0];
    float* out = (float*)d_out;
    const int n_batches = in_sizes[0] >> 16;   // elements / (256*256)

    // 128 KiB dynamic LDS needs the attribute raised once; fall back to the
    // no-staging instantiation if the runtime refuses.
    static int use_lds = -1;
    if (use_lds < 0) {
        hipError_t e = hipFuncSetAttribute(
            reinterpret_cast<const void*>(greedy_perm_kernel<RST>),
            hipFuncAttributeMaxDynamicSharedMemorySize, RST * 256 * 4);
        use_lds = (e == hipSuccess) ? 1 : 0;
    }
    if (use_lds)
        greedy_perm_kernel<RST><<<n_batches, 64, RST * 256 * 4, stream>>>(soft, out);
    else
        greedy_perm_kernel<0><<<n_batches, 64, 0, stream>>>(soft, out);
}

// Round 4
// 293.151 us; speedup vs baseline: 1.8956x; 1.1688x over previous
//
#include <hip/hip_runtime.h>
#include <math.h>

#define NEGINF (-INFINITY)
#define NEGINF_BITS ((int)0xFF800000)

typedef unsigned int u32;
typedef unsigned long long u64;

#define RST 128  // rows staged in LDS (128 KiB dynamic shared)

// One DPP max stage: x = max(x, lanes-moved(x)). bound_ctrl=false + old=x makes
// invalid source lanes contribute x itself (identity for max).
template <int CTRL>
__device__ __forceinline__ float dppmax(float x) {
    int xi = __float_as_int(x);
    int yi = __builtin_amdgcn_update_dpp(xi, xi, CTRL, 0xf, 0xf, false);
    return fmaxf(x, __int_as_float(yi));
}

// Wave64 max via DPP: row_shr 1/2/4/8 then row_bcast 15/31, broadcast from lane 63.
__device__ __forceinline__ float wave_max64(float x) {
    x = dppmax<0x111>(x);   // row_shr:1
    x = dppmax<0x112>(x);   // row_shr:2
    x = dppmax<0x114>(x);   // row_shr:4
    x = dppmax<0x118>(x);   // row_shr:8
    x = dppmax<0x142>(x);   // row_bcast:15
    x = dppmax<0x143>(x);   // row_bcast:31
    return __int_as_float(__builtin_amdgcn_readlane(__float_as_int(x), 63));
}

// Wave argmax over (v, idx), tie-break lowest idx (matches jnp.argmax
// first-occurrence). Fast path: single lane holds the max -> one readlane.
__device__ __forceinline__ void wave_argmax(float v, int idx, float& out_v, int& out_idx) {
    float mv = wave_max64(v);
    u64 mask = __ballot(v == mv);
    int ln = (int)__builtin_ctzll(mask);
    int bi = __builtin_amdgcn_readlane(idx, ln);
    u64 rest = mask & (mask - 1);
    if (rest) {                       // wave-uniform, almost never taken
        while (rest) {
            int l2 = (int)__builtin_ctzll(rest); rest &= rest - 1;
            int b2 = __builtin_amdgcn_readlane(idx, l2);
            if (b2 < bi) bi = b2;
        }
    }
    out_v = mv; out_idx = bi;
}

// Joint top-2 wave reduction over a SINGLE ROW's 256 values, given lane-local
// top-2 (lv,lf) >= (lv2,lf2) with first-occurrence ordering (lf < lf2 on
// equal values). One 6-stage DPP chain carries (top, second); DPP old =
// NEGINF so invalid source lanes inject the neutral element (a copied 'top'
// would wrongly promote into 'second'). Index recovery: lowest lane = lowest
// col (single row => flat = col), within-lane lf precedes lf2.
// Outputs: exact row (max nv, first col nc) and runner-up (nv2, nc2);
// nc2 == 300 when no live runner-up (softmax values are > 0).
__device__ __forceinline__ void wave_top2(float lv, int lf, float lv2, int lf2,
                                          float& nv, int& nc, float& nv2, int& nc2) {
    float av = lv, bv = lv2;
#define T2STAGE(CTRL) {                                                        \
        float a2 = __int_as_float(__builtin_amdgcn_update_dpp(                 \
            NEGINF_BITS, __float_as_int(av), CTRL, 0xf, 0xf, false));          \
        float b2 = __int_as_float(__builtin_amdgcn_update_dpp(                 \
            NEGINF_BITS, __float_as_int(bv), CTRL, 0xf, 0xf, false));          \
        float t = fminf(av, a2);                                               \
        av = fmaxf(av, a2);                                                    \
        bv = fmaxf(fmaxf(bv, b2), t); }
    T2STAGE(0x111) T2STAGE(0x112) T2STAGE(0x114) T2STAGE(0x118)
    T2STAGE(0x142) T2STAGE(0x143)
#undef T2STAGE
    nv = __int_as_float(__builtin_amdgcn_readlane(__float_as_int(av), 63));
    float sv = __int_as_float(__builtin_amdgcn_readlane(__float_as_int(bv), 63));

    u64 m1 = __ballot(lv == nv);
    int ln = (int)__builtin_ctzll(m1);
    nc = __builtin_amdgcn_readlane(lf, ln);

    nv2 = sv; nc2 = 300;
    if (sv > 0.f) {
        if (sv == nv) {
            // duplicate max. Lanes with lv2==nv are a subset of lanes with
            // lv==nv, so candidates: lane ln's lf2 (lowest cols) if its
            // lv2==nv, else the next lane in m1.
            int b2i = __builtin_amdgcn_readlane(__float_as_int(lv2), ln);
            if (__int_as_float(b2i) == nv) {
                nc2 = __builtin_amdgcn_readlane(lf2, ln);
            } else {
                u64 rest = m1 & (m1 - 1);
                int l2 = (int)__builtin_ctzll(rest);
                nc2 = __builtin_amdgcn_readlane(lf, l2);
            }
        } else {
            u64 m2 = __ballot(lv == sv || lv2 == sv);
            int l2 = (int)__builtin_ctzll(m2);
            int tli = __builtin_amdgcn_readlane(__float_as_int(lv), l2);
            nc2 = (__int_as_float(tli) == sv)
                      ? __builtin_amdgcn_readlane(lf, l2)
                      : __builtin_amdgcn_readlane(lf2, l2);
        }
    }
}

// One wave (64 lanes) per batch. Lane l owns rows {j*64+l : j=0..3}:
//   rv[j]/rc[j] : row's current best (max value, argmax col) over untaken cols.
//                 rc==300 => row DEAD (assigned), rv=NEGINF.
//   sv[j]/scc[j]: row's spare = exact runner-up over untaken cols, maintained
//                 eagerly (scc invalidated the step its col is taken).
//                 scc==300 => no spare.
// Lane l also owns the taken-bits for cols 4l..4l+3 (colmask).
// Dirty row (best col taken): live spare -> in-register advance (exact);
// otherwise cooperative rescan (LDS for rows < RSTT, global beyond) with a
// single joint top-2 reduction that refills the spare.
template <int RSTT>
__global__ __launch_bounds__(64, 1) void greedy_perm_kernel(
        const float* __restrict__ soft, float* __restrict__ out) {
    extern __shared__ float smem[];               // RSTT rows x 256 floats
    const int b = blockIdx.x;
    const int lane = threadIdx.x;
    const size_t base = (size_t)b << 16;          // b * 256 * 256
    const float* sc = soft + base;
    float* ob = out + base;

    float rv[4], sv[4];
    int   rc[4], scc[4];
#pragma unroll
    for (int j = 0; j < 4; ++j) { rv[j] = NEGINF; rc[j] = 0; sv[j] = NEGINF; scc[j] = 300; }

    const float4 zero4 = make_float4(0.f, 0.f, 0.f, 0.f);

    // ---- initial per-row top-2 scan, 16 loads in flight, fused zero-fill of
    // ---- out, fused LDS staging of rows 0..RSTT-1 (chunk-XOR swizzled) ----
    for (int k = 0; k < 64; k += 4) {
        float4 w[4][4];
#pragma unroll
        for (int j = 0; j < 4; ++j) {
            const float4* rp = (const float4*)(sc + (size_t)(j * 64 + lane) * 256);
#pragma unroll
            for (int kk = 0; kk < 4; ++kk) w[j][kk] = rp[k + kk];
        }
#pragma unroll
        for (int j = 0; j < 4; ++j) {
            float4* op = (float4*)(ob + (size_t)(j * 64 + lane) * 256);
#pragma unroll
            for (int kk = 0; kk < 4; ++kk) op[k + kk] = zero4;
        }
        if (RSTT > 0) {
            // rows j*64+lane (j=0,1): store chunk c at slot c^lane -> 64 lanes'
            // 16B writes spread across banks (2 lanes/bank, free).
#pragma unroll
            for (int j = 0; j < 2; ++j) {
                float* lp = &smem[(j * 64 + lane) << 8];
#pragma unroll
                for (int kk = 0; kk < 4; ++kk)
                    *(float4*)&lp[((k + kk) ^ lane) << 2] = w[j][kk];
            }
        }
#pragma unroll
        for (int j = 0; j < 4; ++j) {
#pragma unroll
            for (int kk = 0; kk < 4; ++kk) {
                const float4 ww = w[j][kk];
                const int bc = 4 * (k + kk);
                const float e[4] = {ww.x, ww.y, ww.z, ww.w};
#pragma unroll
                for (int q = 0; q < 4; ++q) {
                    const float x = e[q];
                    const int   cx = bc + q;
                    const bool g1 = x > rv[j];
                    const bool g2 = x > sv[j];
                    sv[j]  = g1 ? rv[j] : (g2 ? x  : sv[j]);
                    scc[j] = g1 ? rc[j] : (g2 ? cx : scc[j]);
                    rv[j]  = g1 ? x  : rv[j];
                    rc[j]  = g1 ? cx : rc[j];
                }
            }
        }
    }

    // Drain zero-stores before any 1.0 store can target the same address.
    __threadfence_block();

    u32 colmask = 0;   // 4 bits: cols 4*lane..4*lane+3 assigned?

    // ---- 256 sequential greedy steps ----
    for (int step = 0; step < 256; ++step) {
        // A: argmax over cached row bests. Row-ascending iteration makes the
        // flat-index tie-break implicit: strict > only.
        float bv = rv[0];
        int   bf = (lane << 8) | (rc[0] & 255);
#pragma unroll
        for (int j = 1; j < 4; ++j) {
            if (rv[j] > bv) { bv = rv[j]; bf = (((j << 6) + lane) << 8) | (rc[j] & 255); }
        }
        float gv; int gf;
        wave_argmax(bv, bf, gv, gf);
        (void)gv;
        const int r  = gf >> 8;
        const int cc = gf & 255;

        if (lane == 0) ob[gf] = 1.0f;            // hard[r][cc] = 1
        if (lane == (r & 63)) {                  // winner row -> dead
            const int rj = r >> 6;
#pragma unroll
            for (int j = 0; j < 4; ++j) if (j == rj) { rv[j] = NEGINF; rc[j] = 300; }
        }
        if (lane == (cc >> 2)) colmask |= 1u << (cc & 3);

        // spare invalidation: a spare whose col was just taken dies (eager).
#pragma unroll
        for (int j = 0; j < 4; ++j) if (scc[j] == cc) scc[j] = 300;

        // dirty rows (best col just taken): one combined ballot skips the
        // whole section on the ~37% of steps where no row is dirty.
        bool dd[4]; bool anyd = false;
#pragma unroll
        for (int j = 0; j < 4; ++j) { dd[j] = (rc[j] == cc); anyd |= dd[j]; }
        if (__ballot(anyd)) {
#pragma unroll
            for (int j = 0; j < 4; ++j) {
                const bool need = dd[j] && (scc[j] == 300);
                if (dd[j] && !need) {            // exact in-register advance
                    rv[j] = sv[j]; rc[j] = scc[j];
                    sv[j] = NEGINF; scc[j] = 300;
                }
                u64 m = __ballot(need);
                while (m) {
                    const int ln = (int)__builtin_ctzll(m); m &= m - 1;
                    const int row = (j << 6) + ln;
                    // coalesced: 64 lanes x float4 = the whole 256-float row
                    float4 w = (RSTT > 0 && row < RSTT)
                        ? *(const float4*)&smem[(row << 8) | (((lane ^ ln) & 63) << 2)]
                        : *(const float4*)(sc + ((size_t)row << 8) + (lane << 2));
                    const float q0 = (colmask & 1u) ? NEGINF : w.x;
                    const float q1 = (colmask & 2u) ? NEGINF : w.y;
                    const float q2 = (colmask & 4u) ? NEGINF : w.z;
                    const float q3 = (colmask & 8u) ? NEGINF : w.w;
                    // lane-local top-2, first-occurrence (strict >)
                    const int cb = lane << 2;
                    float lv = q0; int lf = cb;
                    float lv2 = NEGINF; int lf2 = cb;
                    {
                        bool g1 = q1 > lv, g2 = q1 > lv2;
                        lv2 = g1 ? lv : (g2 ? q1 : lv2); lf2 = g1 ? lf : (g2 ? cb + 1 : lf2);
                        lv  = g1 ? q1 : lv;              lf  = g1 ? cb + 1 : lf;
                        g1 = q2 > lv; g2 = q2 > lv2;
                        lv2 = g1 ? lv : (g2 ? q2 : lv2); lf2 = g1 ? lf : (g2 ? cb + 2 : lf2);
                        lv  = g1 ? q2 : lv;              lf  = g1 ? cb + 2 : lf;
                        g1 = q3 > lv; g2 = q3 > lv2;
                        lv2 = g1 ? lv : (g2 ? q3 : lv2); lf2 = g1 ? lf : (g2 ? cb + 3 : lf2);
                        lv  = g1 ? q3 : lv;              lf  = g1 ? cb + 3 : lf;
                    }
                    float nv, nv2; int nc, nc2;
                    wave_top2(lv, lf, lv2, lf2, nv, nc, nv2, nc2);
                    if (lane == ln) {
#pragma unroll
                        for (int jj = 0; jj < 4; ++jj) if (jj == j) {
                            rv[jj] = nv; rc[jj] = nc;
                            sv[jj] = nv2; scc[jj] = nc2;   // nc2==300 if none
                        }
                    }
                }
            }
        }
    }
}

extern "C" void kernel_launch(void* const* d_in, const int* in_sizes, int n_in,
                              void* d_out, int out_size, void* d_ws, size_t ws_size,
                              hipStream_t stream) {
    const float* soft = (const float*)d_in[0];
    float* out = (float*)d_out;
    const int n_batches = in_sizes[0] >> 16;   // elements / (256*256)

    // 128 KiB dynamic LDS needs the attribute raised once; fall back to the
    // no-staging instantiation if the runtime refuses.
    static int use_lds = -1;
    if (use_lds < 0) {
        hipError_t e = hipFuncSetAttribute(
            reinterpret_cast<const void*>(greedy_perm_kernel<RST>),
            hipFuncAttributeMaxDynamicSharedMemorySize, RST * 256 * 4);
        use_lds = (e == hipSuccess) ? 1 : 0;
    }
    if (use_lds)
        greedy_perm_kernel<RST><<<n_batches, 64, RST * 256 * 4, stream>>>(soft, out);
    else
        greedy_perm_kernel<0><<<n_batches, 64, 0, stream>>>(soft, out);
}